// Round 1
// baseline (757.878 us; speedup 1.0000x reference)
//
#include <hip/hip_runtime.h>

typedef __attribute__((ext_vector_type(8))) short short8;
typedef __attribute__((ext_vector_type(4))) float f32x4;
typedef __attribute__((ext_vector_type(8))) unsigned short u16x8;

#define B_ 4
#define S_ 2048
#define EMB_ 512
#define HID_ 512
#define VOCAB_ 32000
#define ROWS (B_ * S_)          // 8192
#define NCHUNK 32
#define CHUNK 64                // NCHUNK*CHUNK == S_

__device__ __forceinline__ unsigned short f2bf(float f) {
    unsigned int u = __float_as_uint(f);
    u += 0x7fffu + ((u >> 16) & 1u);
    return (unsigned short)(u >> 16);
}

__device__ __forceinline__ void gl_lds16(const unsigned short* g, unsigned short* l) {
    __builtin_amdgcn_global_load_lds(
        (const __attribute__((address_space(1))) unsigned int*)(uintptr_t)(g),
        (__attribute__((address_space(3))) unsigned int*)(unsigned int)(uintptr_t)(l),
        16, 0, 0);
}

// ---------------- transpose + f32->bf16 convert: src[K][N] -> dst[N][K] ----------------
__global__ __launch_bounds__(256) void transpose_convert_k(
    const float* __restrict__ src, unsigned short* __restrict__ dst, int K, int N) {
    __shared__ float t[32][33];
    int kt = blockIdx.y * 32, nt = blockIdx.x * 32;
    int tx = threadIdx.x, ty = threadIdx.y;   // block (32,8)
#pragma unroll
    for (int i = 0; i < 4; i++) {
        int k = kt + ty + i * 8;
        t[ty + i * 8][tx] = src[(size_t)k * N + nt + tx];
    }
    __syncthreads();
#pragma unroll
    for (int i = 0; i < 4; i++) {
        int n = nt + ty + i * 8;
        dst[(size_t)n * K + kt + tx] = f2bf(t[tx][ty + i * 8]);
    }
}

// ---------------- embedding gather + LayerNorm (eps=1e-5); writes raw x and normed bf16 ----------------
__global__ __launch_bounds__(256) void embed_ln_k(
    const int* __restrict__ ids, const float* __restrict__ emb,
    const float* __restrict__ gam, const float* __restrict__ bet,
    float* __restrict__ xres, unsigned short* __restrict__ xw) {
    int row = blockIdx.x * 4 + (threadIdx.x >> 6);
    int lane = threadIdx.x & 63;
    const float4* src = (const float4*)(emb + (size_t)ids[row] * EMB_);
    float v[8];
    *(float4*)(v) = src[lane * 2];
    *(float4*)(v + 4) = src[lane * 2 + 1];
    float s = 0.f, s2 = 0.f;
#pragma unroll
    for (int j = 0; j < 8; j++) { s += v[j]; s2 += v[j] * v[j]; }
#pragma unroll
    for (int off = 1; off < 64; off <<= 1) {
        s += __shfl_xor(s, off);
        s2 += __shfl_xor(s2, off);
    }
    float mu = s * (1.f / EMB_);
    float var = fmaxf(s2 * (1.f / EMB_) - mu * mu, 0.f);
    float rstd = rsqrtf(var + 1e-5f);
    float4* xr = (float4*)(xres + (size_t)row * EMB_);
    xr[lane * 2] = *(float4*)(v);
    xr[lane * 2 + 1] = *(float4*)(v + 4);
    u16x8 o;
#pragma unroll
    for (int j = 0; j < 8; j++) {
        int c = lane * 8 + j;
        o[j] = f2bf((v[j] - mu) * rstd * gam[c] + bet[c]);
    }
    *(u16x8*)(xw + (size_t)row * EMB_ + lane * 8) = o;
}

// ---------------- LayerNorm of xsrc -> bf16 xw ----------------
__global__ __launch_bounds__(256) void ln_k(
    const float* __restrict__ xsrc,
    const float* __restrict__ gam, const float* __restrict__ bet,
    unsigned short* __restrict__ xw, float eps) {
    int row = blockIdx.x * 4 + (threadIdx.x >> 6);
    int lane = threadIdx.x & 63;
    const float4* src = (const float4*)(xsrc + (size_t)row * HID_);
    float v[8];
    *(float4*)(v) = src[lane * 2];
    *(float4*)(v + 4) = src[lane * 2 + 1];
    float s = 0.f, s2 = 0.f;
#pragma unroll
    for (int j = 0; j < 8; j++) { s += v[j]; s2 += v[j] * v[j]; }
#pragma unroll
    for (int off = 1; off < 64; off <<= 1) {
        s += __shfl_xor(s, off);
        s2 += __shfl_xor(s2, off);
    }
    float mu = s * (1.f / HID_);
    float var = fmaxf(s2 * (1.f / HID_) - mu * mu, 0.f);
    float rstd = rsqrtf(var + eps);
    u16x8 o;
#pragma unroll
    for (int j = 0; j < 8; j++) {
        int c = lane * 8 + j;
        o[j] = f2bf((v[j] - mu) * rstd * gam[c] + bet[c]);
    }
    *(u16x8*)(xw + (size_t)row * HID_ + lane * 8) = o;
}

// ---------------- GEMM: A[M][K] bf16 x Bt[N][K] bf16 -> C[M][N] f32 (+bias) ----------------
// 128x128 tile, BK=64, 256 threads = 4 waves (2x2), wave computes 64x64.
__global__ __launch_bounds__(256) void gemm_bf16_k(
    const unsigned short* __restrict__ A, const unsigned short* __restrict__ Bt,
    const float* __restrict__ bias, float* __restrict__ C,
    int M, int N, int K) {
    __shared__ unsigned short lA[128 * 64];
    __shared__ unsigned short lB[128 * 64];
    int tid = threadIdx.x;
    int w = tid >> 6, l = tid & 63;
    int m0 = blockIdx.y * 128, n0 = blockIdx.x * 128;
    int wm = w >> 1, wn = w & 1;
    f32x4 acc[4][4] = {};

    int rIn = l >> 3;             // 0..7 row within 8-row chunk
    int cOff = (l & 7) * 8;       // bf16 col offset within 64-wide k slab

    for (int k0 = 0; k0 < K; k0 += 64) {
#pragma unroll
        for (int i = 0; i < 4; i++) {
            int c = w * 4 + i;                     // chunk 0..15 (8 rows each)
            gl_lds16(A + (size_t)(m0 + c * 8 + rIn) * K + k0 + cOff, &lA[c * 512]);
            gl_lds16(Bt + (size_t)(n0 + c * 8 + rIn) * K + k0 + cOff, &lB[c * 512]);
        }
        asm volatile("s_waitcnt vmcnt(0)" ::: "memory");
        __syncthreads();

        const unsigned short* pa = lA + ((size_t)(wm * 64 + (l & 15)) * 64) + ((l >> 4) * 8);
        const unsigned short* pb = lB + ((size_t)(wn * 64 + (l & 15)) * 64) + ((l >> 4) * 8);
#pragma unroll
        for (int kk = 0; kk < 2; kk++) {
            short8 af[4], bfr[4];
#pragma unroll
            for (int m = 0; m < 4; m++) af[m] = *(const short8*)(pa + m * 16 * 64 + kk * 32);
#pragma unroll
            for (int n = 0; n < 4; n++) bfr[n] = *(const short8*)(pb + n * 16 * 64 + kk * 32);
#pragma unroll
            for (int m = 0; m < 4; m++)
#pragma unroll
                for (int n = 0; n < 4; n++)
                    acc[m][n] = __builtin_amdgcn_mfma_f32_16x16x32_bf16(af[m], bfr[n], acc[m][n], 0, 0, 0);
        }
        __syncthreads();
    }

#pragma unroll
    for (int m = 0; m < 4; m++) {
        int rbase = m0 + wm * 64 + m * 16 + ((l >> 4) * 4);
#pragma unroll
        for (int n = 0; n < 4; n++) {
            int col = n0 + wn * 64 + n * 16 + (l & 15);
            float bs = bias ? bias[col] : 0.f;
#pragma unroll
            for (int j = 0; j < 4; j++)
                C[(size_t)(rbase + j) * N + col] = acc[m][n][j] + bs;
        }
    }
}

// ---------------- minGRU chunked scan ----------------
// proj[row][0..511]=k (gate pre-act), proj[row][512..1023]=h_pre (candidate)
__device__ __forceinline__ void gate_terms(float k, float hp, float& a, float& b) {
    float z = 1.f / (1.f + __expf(-k));   // sigmoid(k)
    a = 1.f - z;                          // sigmoid(-k)
    float g = (hp >= 0.f) ? (hp + 0.5f) : (1.f / (1.f + __expf(-hp)));
    b = z * g;
}

// phase 1: per (b,chunk,h): local prefix with h_in=0 -> A = prod a, Bc = local end state
__global__ __launch_bounds__(256) void scan1_k(
    const float* __restrict__ proj, float* __restrict__ Ach, float* __restrict__ Bch) {
    int t = blockIdx.x * 256 + threadIdx.x;   // 65536
    int h = t & (HID_ - 1);
    int bc = t >> 9;                          // b*NCHUNK + c
    int b = bc >> 5, c = bc & (NCHUNK - 1);
    const float* p = proj + ((size_t)(b * S_ + c * CHUNK)) * (2 * HID_) + h;
    float A = 1.f, H = 0.f;
#pragma unroll 4
    for (int s = 0; s < CHUNK; s++) {
        float k = p[(size_t)s * (2 * HID_)];
        float hp = p[(size_t)s * (2 * HID_) + HID_];
        float a, bb;
        gate_terms(k, hp, a, bb);
        H = a * H + bb;
        A *= a;
    }
    Ach[t] = A;
    Bch[t] = H;
}

// phase 2: per (b,h): scan across chunk summaries -> Hin[b][c][h] = h entering chunk c
__global__ __launch_bounds__(256) void scan2_k(
    const float* __restrict__ Ach, const float* __restrict__ Bch, float* __restrict__ Hin) {
    int t = blockIdx.x * 256 + threadIdx.x;   // 2048
    int b = t >> 9, h = t & (HID_ - 1);
    float carry = 0.f;
#pragma unroll
    for (int c = 0; c < NCHUNK; c++) {
        int idx = (b * NCHUNK + c) * HID_ + h;
        Hin[idx] = carry;
        carry = Ach[idx] * carry + Bch[idx];
    }
}

// phase 3: recompute local recurrence with true h_in; xres += h (residual)
__global__ __launch_bounds__(256) void scan3_k(
    const float* __restrict__ proj, const float* __restrict__ Hin, float* __restrict__ xres) {
    int t = blockIdx.x * 256 + threadIdx.x;
    int h = t & (HID_ - 1);
    int bc = t >> 9;
    int b = bc >> 5, c = bc & (NCHUNK - 1);
    const float* p = proj + ((size_t)(b * S_ + c * CHUNK)) * (2 * HID_) + h;
    float* x = xres + ((size_t)(b * S_ + c * CHUNK)) * HID_ + h;
    float H = Hin[t];
#pragma unroll 4
    for (int s = 0; s < CHUNK; s++) {
        float k = p[(size_t)s * (2 * HID_)];
        float hp = p[(size_t)s * (2 * HID_) + HID_];
        float a, bb;
        gate_terms(k, hp, a, bb);
        H = a * H + bb;
        x[(size_t)s * HID_] += H;
    }
}

// ---------------- launch ----------------
extern "C" void kernel_launch(void* const* d_in, const int* in_sizes, int n_in,
                              void* d_out, int out_size, void* d_ws, size_t ws_size,
                              hipStream_t stream) {
    const int* ids = (const int*)d_in[0];
    const float* emb = (const float*)d_in[1];
    const float* W0 = (const float*)d_in[2];
    const float* W1 = (const float*)d_in[3];
    const float* ln0_g = (const float*)d_in[4];
    const float* ln0_b = (const float*)d_in[5];
    const float* ln1_g = (const float*)d_in[6];
    const float* ln1_b = (const float*)d_in[7];
    const float* lnf_g = (const float*)d_in[8];
    const float* lnf_b = (const float*)d_in[9];
    const float* fc_w = (const float*)d_in[10];
    const float* fc_b = (const float*)d_in[11];
    float* out = (float*)d_out;

    char* ws = (char*)d_ws;
    const size_t OFF_XW   = 0;                          // bf16 [8192][512]   8.4 MB
    const size_t OFF_PROJ = 8388608;                    // f32  [8192][1024] 33.6 MB
    const size_t OFF_XRES = OFF_PROJ + 33554432;        // f32  [8192][512]  16.8 MB
    const size_t OFF_WT   = OFF_XRES + 16777216;        // bf16 [1024][512]   1.05 MB
    const size_t OFF_SA   = OFF_WT + 1048576;
    const size_t OFF_SB   = OFF_SA + 262144;
    const size_t OFF_SH   = OFF_SB + 262144;

    unsigned short* xw  = (unsigned short*)(ws + OFF_XW);
    float* proj         = (float*)(ws + OFF_PROJ);
    float* xres         = (float*)(ws + OFF_XRES);
    unsigned short* wt  = (unsigned short*)(ws + OFF_WT);
    unsigned short* fcwt = (unsigned short*)(ws + OFF_PROJ);  // reuse proj after scans
    float* sA = (float*)(ws + OFF_SA);
    float* sB = (float*)(ws + OFF_SB);
    float* sH = (float*)(ws + OFF_SH);

    dim3 tb(32, 8);

    // layer 0
    embed_ln_k<<<ROWS / 4, 256, 0, stream>>>(ids, emb, ln0_g, ln0_b, xres, xw);
    transpose_convert_k<<<dim3(1024 / 32, 512 / 32), tb, 0, stream>>>(W0, wt, 512, 1024);
    gemm_bf16_k<<<dim3(1024 / 128, ROWS / 128), 256, 0, stream>>>(xw, wt, nullptr, proj, ROWS, 1024, 512);
    scan1_k<<<65536 / 256, 256, 0, stream>>>(proj, sA, sB);
    scan2_k<<<2048 / 256, 256, 0, stream>>>(sA, sB, sH);
    scan3_k<<<65536 / 256, 256, 0, stream>>>(proj, sH, xres);

    // layer 1
    ln_k<<<ROWS / 4, 256, 0, stream>>>(xres, ln1_g, ln1_b, xw, 1e-5f);
    transpose_convert_k<<<dim3(1024 / 32, 512 / 32), tb, 0, stream>>>(W1, wt, 512, 1024);
    gemm_bf16_k<<<dim3(1024 / 128, ROWS / 128), 256, 0, stream>>>(xw, wt, nullptr, proj, ROWS, 1024, 512);
    scan1_k<<<65536 / 256, 256, 0, stream>>>(proj, sA, sB);
    scan2_k<<<2048 / 256, 256, 0, stream>>>(sA, sB, sH);
    scan3_k<<<65536 / 256, 256, 0, stream>>>(proj, sH, xres);

    // final LN (eps=0.0) + logits
    ln_k<<<ROWS / 4, 256, 0, stream>>>(xres, lnf_g, lnf_b, xw, 0.0f);
    transpose_convert_k<<<dim3(VOCAB_ / 32, 512 / 32), tb, 0, stream>>>(fc_w, fcwt, 512, VOCAB_);
    gemm_bf16_k<<<dim3(VOCAB_ / 128, ROWS / 128), 256, 0, stream>>>(xw, fcwt, fc_b, out, ROWS, VOCAB_, 512);
}

// Round 2
// 687.073 us; speedup vs baseline: 1.1031x; 1.1031x over previous
//
#include <hip/hip_runtime.h>

typedef __attribute__((ext_vector_type(8))) short short8;
typedef __attribute__((ext_vector_type(4))) float f32x4;
typedef __attribute__((ext_vector_type(8))) unsigned short u16x8;

#define B_ 4
#define S_ 2048
#define EMB_ 512
#define HID_ 512
#define VOCAB_ 32000
#define ROWS (B_ * S_)          // 8192
#define NCHUNK 32
#define CHUNK 64                // NCHUNK*CHUNK == S_

__device__ __forceinline__ unsigned short f2bf(float f) {
    unsigned int u = __float_as_uint(f);
    u += 0x7fffu + ((u >> 16) & 1u);
    return (unsigned short)(u >> 16);
}

__device__ __forceinline__ void gl_lds16(const unsigned short* g, unsigned short* l) {
    __builtin_amdgcn_global_load_lds(
        (const __attribute__((address_space(1))) unsigned int*)(uintptr_t)(g),
        (__attribute__((address_space(3))) unsigned int*)(unsigned int)(uintptr_t)(l),
        16, 0, 0);
}

// ---------------- transpose + f32->bf16 convert: src[K][N] -> dst[N][K] ----------------
__global__ __launch_bounds__(256) void transpose_convert_k(
    const float* __restrict__ src, unsigned short* __restrict__ dst, int K, int N) {
    __shared__ float t[32][33];
    int kt = blockIdx.y * 32, nt = blockIdx.x * 32;
    int tx = threadIdx.x, ty = threadIdx.y;   // block (32,8)
#pragma unroll
    for (int i = 0; i < 4; i++) {
        int k = kt + ty + i * 8;
        t[ty + i * 8][tx] = src[(size_t)k * N + nt + tx];
    }
    __syncthreads();
#pragma unroll
    for (int i = 0; i < 4; i++) {
        int n = nt + ty + i * 8;
        dst[(size_t)n * K + kt + tx] = f2bf(t[tx][ty + i * 8]);
    }
}

// ---------------- embedding gather + LayerNorm (eps=1e-5); writes raw x and normed bf16 ----------------
__global__ __launch_bounds__(256) void embed_ln_k(
    const int* __restrict__ ids, const float* __restrict__ emb,
    const float* __restrict__ gam, const float* __restrict__ bet,
    float* __restrict__ xres, unsigned short* __restrict__ xw) {
    int row = blockIdx.x * 4 + (threadIdx.x >> 6);
    int lane = threadIdx.x & 63;
    const float4* src = (const float4*)(emb + (size_t)ids[row] * EMB_);
    float v[8];
    *(float4*)(v) = src[lane * 2];
    *(float4*)(v + 4) = src[lane * 2 + 1];
    float s = 0.f, s2 = 0.f;
#pragma unroll
    for (int j = 0; j < 8; j++) { s += v[j]; s2 += v[j] * v[j]; }
#pragma unroll
    for (int off = 1; off < 64; off <<= 1) {
        s += __shfl_xor(s, off);
        s2 += __shfl_xor(s2, off);
    }
    float mu = s * (1.f / EMB_);
    float var = fmaxf(s2 * (1.f / EMB_) - mu * mu, 0.f);
    float rstd = rsqrtf(var + 1e-5f);
    float4* xr = (float4*)(xres + (size_t)row * EMB_);
    xr[lane * 2] = *(float4*)(v);
    xr[lane * 2 + 1] = *(float4*)(v + 4);
    u16x8 o;
#pragma unroll
    for (int j = 0; j < 8; j++) {
        int c = lane * 8 + j;
        o[j] = f2bf((v[j] - mu) * rstd * gam[c] + bet[c]);
    }
    *(u16x8*)(xw + (size_t)row * EMB_ + lane * 8) = o;
}

// ---------------- LayerNorm of xsrc -> bf16 xw ----------------
__global__ __launch_bounds__(256) void ln_k(
    const float* __restrict__ xsrc,
    const float* __restrict__ gam, const float* __restrict__ bet,
    unsigned short* __restrict__ xw, float eps) {
    int row = blockIdx.x * 4 + (threadIdx.x >> 6);
    int lane = threadIdx.x & 63;
    const float4* src = (const float4*)(xsrc + (size_t)row * HID_);
    float v[8];
    *(float4*)(v) = src[lane * 2];
    *(float4*)(v + 4) = src[lane * 2 + 1];
    float s = 0.f, s2 = 0.f;
#pragma unroll
    for (int j = 0; j < 8; j++) { s += v[j]; s2 += v[j] * v[j]; }
#pragma unroll
    for (int off = 1; off < 64; off <<= 1) {
        s += __shfl_xor(s, off);
        s2 += __shfl_xor(s2, off);
    }
    float mu = s * (1.f / HID_);
    float var = fmaxf(s2 * (1.f / HID_) - mu * mu, 0.f);
    float rstd = rsqrtf(var + eps);
    u16x8 o;
#pragma unroll
    for (int j = 0; j < 8; j++) {
        int c = lane * 8 + j;
        o[j] = f2bf((v[j] - mu) * rstd * gam[c] + bet[c]);
    }
    *(u16x8*)(xw + (size_t)row * HID_ + lane * 8) = o;
}

// ---------------- small GEMM (layers): A[M][K] bf16 x Bt[N][K] bf16 -> C[M][N] f32 ----------------
// 128x128 tile, BK=64, 256 threads = 4 waves (2x2), wave computes 64x64.  (validated r1)
__global__ __launch_bounds__(256) void gemm_bf16_k(
    const unsigned short* __restrict__ A, const unsigned short* __restrict__ Bt,
    const float* __restrict__ bias, float* __restrict__ C,
    int M, int N, int K) {
    __shared__ unsigned short lA[128 * 64];
    __shared__ unsigned short lB[128 * 64];
    int tid = threadIdx.x;
    int w = tid >> 6, l = tid & 63;
    int m0 = blockIdx.y * 128, n0 = blockIdx.x * 128;
    int wm = w >> 1, wn = w & 1;
    f32x4 acc[4][4] = {};

    int rIn = l >> 3;
    int cOff = (l & 7) * 8;

    for (int k0 = 0; k0 < K; k0 += 64) {
#pragma unroll
        for (int i = 0; i < 4; i++) {
            int c = w * 4 + i;
            gl_lds16(A + (size_t)(m0 + c * 8 + rIn) * K + k0 + cOff, &lA[c * 512]);
            gl_lds16(Bt + (size_t)(n0 + c * 8 + rIn) * K + k0 + cOff, &lB[c * 512]);
        }
        asm volatile("s_waitcnt vmcnt(0)" ::: "memory");
        __syncthreads();

        const unsigned short* pa = lA + ((size_t)(wm * 64 + (l & 15)) * 64) + ((l >> 4) * 8);
        const unsigned short* pb = lB + ((size_t)(wn * 64 + (l & 15)) * 64) + ((l >> 4) * 8);
#pragma unroll
        for (int kk = 0; kk < 2; kk++) {
            short8 af[4], bfr[4];
#pragma unroll
            for (int m = 0; m < 4; m++) af[m] = *(const short8*)(pa + m * 16 * 64 + kk * 32);
#pragma unroll
            for (int n = 0; n < 4; n++) bfr[n] = *(const short8*)(pb + n * 16 * 64 + kk * 32);
#pragma unroll
            for (int m = 0; m < 4; m++)
#pragma unroll
                for (int n = 0; n < 4; n++)
                    acc[m][n] = __builtin_amdgcn_mfma_f32_16x16x32_bf16(af[m], bfr[n], acc[m][n], 0, 0, 0);
        }
        __syncthreads();
    }

#pragma unroll
    for (int m = 0; m < 4; m++) {
        int rbase = m0 + wm * 64 + m * 16 + ((l >> 4) * 4);
#pragma unroll
        for (int n = 0; n < 4; n++) {
            int col = n0 + wn * 64 + n * 16 + (l & 15);
            float bs = bias ? bias[col] : 0.f;
#pragma unroll
            for (int j = 0; j < 4; j++)
                C[(size_t)(rbase + j) * N + col] = acc[m][n][j] + bs;
        }
    }
}

// ---------------- big GEMM: 256x256 tile, BK=64, 8 waves, 8-phase pipeline, st_16x32 swizzle ----
// LDS layout per 256x64 bf16 tile: subtiled [r/16][c/32][16][32], within-subtile byte
//   = in_r*64 + ((c&31) ^ ((in_r&8)?16:0))*2.  Two tiles (A,B) x double buffer = 128 KiB.
// Staging: global_load_lds writes LINEAR; per-lane global src is inverse-swizzled (rule #21).
// Half-tile (128 rows, 16KB) = 2 gl_lds calls (8KB each, 512 thr x 16B).
// Schedule: tile T's 4 halves issue at (T-2,p2),(T-2,p3),(T-1,p0),(T-1,p1);
//   vmcnt(4) once per tile at p3 -> next tile fully landed, 2 halves stay in flight.
__device__ __forceinline__ void stage_half(
    const unsigned short* __restrict__ A, const unsigned short* __restrict__ Bt,
    int K, int m0, int n0, int nt, int H,
    char* smem, int r0, int c0, unsigned wq) {
    if (H >= 4 * nt) return;
    int T = H >> 2, j = H & 3;
    const unsigned short* src = (j < 2) ? A : Bt;
    int row0 = ((j < 2) ? m0 : n0) + ((j & 1) << 7);
    int k0 = T << 6;
    unsigned tb = ((unsigned)(T & 1) << 16) | ((unsigned)(j >> 1) << 15) | ((unsigned)(j & 1) << 14);
    const unsigned short* g0 = src + (size_t)(row0 + r0) * K + (k0 + c0);
    gl_lds16(g0, (unsigned short*)(smem + tb + wq));                     // q=0 (rows r0)
    gl_lds16(g0 + (size_t)64 * K, (unsigned short*)(smem + tb + 8192 + wq)); // q=1 (rows r0+64)
}

#define MIDBAR() __builtin_amdgcn_s_barrier()
#define ENDBAR() do { asm volatile("s_waitcnt lgkmcnt(0)" ::: "memory"); \
                      asm volatile("s_barrier" ::: "memory"); } while (0)

#define PHASE_MFMA(AF, BF, MO, NO)                                                  \
    do {                                                                            \
        __builtin_amdgcn_s_setprio(1);                                             \
        _Pragma("unroll") for (int mf = 0; mf < 4; ++mf)                            \
        _Pragma("unroll") for (int nf = 0; nf < 2; ++nf)                            \
        _Pragma("unroll") for (int ks = 0; ks < 2; ++ks)                            \
            acc[(MO) + mf][(NO) + nf] = __builtin_amdgcn_mfma_f32_16x16x32_bf16(    \
                AF[mf][ks], BF[nf][ks], acc[(MO) + mf][(NO) + nf], 0, 0, 0);        \
        __builtin_amdgcn_s_setprio(0);                                             \
    } while (0)

__global__ __launch_bounds__(512, 2) void gemm256_bf16_k(
    const unsigned short* __restrict__ A, const unsigned short* __restrict__ Bt,
    const float* __restrict__ bias, float* __restrict__ C,
    int M, int N, int K, int nbn) {
    extern __shared__ char smem[];
    int tid = threadIdx.x;
    int w = tid >> 6, l = tid & 63;
    int wm = w >> 2, wn = w & 3;          // 2 x 4 wave grid; wave tile 128(M) x 64(N)

    // T1: XCD-aware swizzle (grid here is always a multiple of 8)
    int nwg = gridDim.x;
    int bid = blockIdx.x;
    int swz = ((nwg & 7) == 0) ? ((bid & 7) * (nwg >> 3) + (bid >> 3)) : bid;
    int bm = swz / nbn, bn = swz % nbn;
    int m0 = bm << 8, n0 = bn << 8;

    // staging decode (per thread): LDS linear off (q*8192 + w*1024 + l*16) -> (row,col)
    int r0 = ((w >> 1) << 4) + (l >> 2);                               // + h*128 at stage
    int c0 = ((w & 1) << 5) + (((l & 3) << 3) ^ ((l & 32) ? 16 : 0));
    unsigned wq = (unsigned)(w << 10);

    // ds_read per-thread byte offset within a subtile row-block
    unsigned rowpart = (unsigned)(((l & 15) << 6) + (((((l >> 4) << 3)) ^ ((l & 8) ? 16 : 0)) << 1));
    unsigned aoff = ((unsigned)wm << 14) + rowpart;            // A tile base for this wave
    unsigned boff = 32768u + ((unsigned)wn << 13) + rowpart;   // B tile base for this wave

    int nt = K >> 6;
    f32x4 acc[8][4] = {};

    // prologue: stage halves 0..5 (tile0 complete + tile1 h0,h1), order pinned
    stage_half(A, Bt, K, m0, n0, nt, 0, smem, r0, c0, wq); asm volatile("" ::: "memory");
    stage_half(A, Bt, K, m0, n0, nt, 1, smem, r0, c0, wq); asm volatile("" ::: "memory");
    stage_half(A, Bt, K, m0, n0, nt, 2, smem, r0, c0, wq); asm volatile("" ::: "memory");
    stage_half(A, Bt, K, m0, n0, nt, 3, smem, r0, c0, wq); asm volatile("" ::: "memory");
    stage_half(A, Bt, K, m0, n0, nt, 4, smem, r0, c0, wq); asm volatile("" ::: "memory");
    stage_half(A, Bt, K, m0, n0, nt, 5, smem, r0, c0, wq);
    asm volatile("s_waitcnt vmcnt(4)" ::: "memory");
    asm volatile("s_barrier" ::: "memory");

    for (int t = 0; t < nt; ++t) {
        const char* pA = smem + (((unsigned)(t & 1)) << 16) + aoff;
        const char* pB = smem + (((unsigned)(t & 1)) << 16) + boff;
        short8 A0[4][2], A1[4][2], B0[2][2], B1[2][2];

        // ---- phase 0: load A-Mhalf0 + B-Nhalf0 (12 ds_read_b128), stage, MFMA Q00
#pragma unroll
        for (int mf = 0; mf < 4; ++mf)
#pragma unroll
            for (int ks = 0; ks < 2; ++ks)
                A0[mf][ks] = *(const short8*)(pA + mf * 2048 + ks * 1024);
#pragma unroll
        for (int nf = 0; nf < 2; ++nf)
#pragma unroll
            for (int ks = 0; ks < 2; ++ks)
                B0[nf][ks] = *(const short8*)(pB + nf * 2048 + ks * 1024);
        stage_half(A, Bt, K, m0, n0, nt, 4 * t + 6, smem, r0, c0, wq);
        MIDBAR();
        PHASE_MFMA(A0, B0, 0, 0);
        ENDBAR();

        // ---- phase 1: load A-Mhalf1 + B-Nhalf1 (12), stage, MFMA Q10
#pragma unroll
        for (int mf = 0; mf < 4; ++mf)
#pragma unroll
            for (int ks = 0; ks < 2; ++ks)
                A1[mf][ks] = *(const short8*)(pA + (4 + mf) * 2048 + ks * 1024);
#pragma unroll
        for (int nf = 0; nf < 2; ++nf)
#pragma unroll
            for (int ks = 0; ks < 2; ++ks)
                B1[nf][ks] = *(const short8*)(pB + (2 + nf) * 2048 + ks * 1024);
        stage_half(A, Bt, K, m0, n0, nt, 4 * t + 7, smem, r0, c0, wq);
        MIDBAR();
        PHASE_MFMA(A1, B0, 4, 0);
        ENDBAR();

        // ---- phase 2: stage (t+2 A-h0: safe, this tile's LDS reads all drained), MFMA Q11
        stage_half(A, Bt, K, m0, n0, nt, 4 * t + 8, smem, r0, c0, wq);
        MIDBAR();
        PHASE_MFMA(A1, B1, 4, 2);
        ENDBAR();

        // ---- phase 3: stage, counted vmcnt, MFMA Q01
        stage_half(A, Bt, K, m0, n0, nt, 4 * t + 9, smem, r0, c0, wq);
        if (t < nt - 2)       { asm volatile("s_waitcnt vmcnt(4)" ::: "memory"); }
        else if (t == nt - 2) { asm volatile("s_waitcnt vmcnt(0)" ::: "memory"); }
        MIDBAR();
        PHASE_MFMA(A0, B1, 0, 2);
        ENDBAR();
    }

    // epilogue: C write (+bias).  row=(l>>4)*4+j, col=l&15 within each 16x16 frag (m89)
    int rbase = m0 + (wm << 7) + ((l >> 4) << 2);
    int cbase = n0 + (wn << 6) + (l & 15);
#pragma unroll
    for (int nf = 0; nf < 4; ++nf) {
        int col = cbase + (nf << 4);
        float bs = bias ? bias[col] : 0.f;
#pragma unroll
        for (int mf = 0; mf < 8; ++mf) {
            int row = rbase + (mf << 4);
#pragma unroll
            for (int j = 0; j < 4; ++j)
                C[(size_t)(row + j) * N + col] = acc[mf][nf][j] + bs;
        }
    }
}

// ---------------- minGRU chunked scan ----------------
__device__ __forceinline__ void gate_terms(float k, float hp, float& a, float& b) {
    float z = 1.f / (1.f + __expf(-k));
    a = 1.f - z;
    float g = (hp >= 0.f) ? (hp + 0.5f) : (1.f / (1.f + __expf(-hp)));
    b = z * g;
}

__global__ __launch_bounds__(256) void scan1_k(
    const float* __restrict__ proj, float* __restrict__ Ach, float* __restrict__ Bch) {
    int t = blockIdx.x * 256 + threadIdx.x;
    int h = t & (HID_ - 1);
    int bc = t >> 9;
    int b = bc >> 5, c = bc & (NCHUNK - 1);
    const float* p = proj + ((size_t)(b * S_ + c * CHUNK)) * (2 * HID_) + h;
    float A = 1.f, H = 0.f;
#pragma unroll 4
    for (int s = 0; s < CHUNK; s++) {
        float k = p[(size_t)s * (2 * HID_)];
        float hp = p[(size_t)s * (2 * HID_) + HID_];
        float a, bb;
        gate_terms(k, hp, a, bb);
        H = a * H + bb;
        A *= a;
    }
    Ach[t] = A;
    Bch[t] = H;
}

__global__ __launch_bounds__(256) void scan2_k(
    const float* __restrict__ Ach, const float* __restrict__ Bch, float* __restrict__ Hin) {
    int t = blockIdx.x * 256 + threadIdx.x;
    int b = t >> 9, h = t & (HID_ - 1);
    float carry = 0.f;
#pragma unroll
    for (int c = 0; c < NCHUNK; c++) {
        int idx = (b * NCHUNK + c) * HID_ + h;
        Hin[idx] = carry;
        carry = Ach[idx] * carry + Bch[idx];
    }
}

__global__ __launch_bounds__(256) void scan3_k(
    const float* __restrict__ proj, const float* __restrict__ Hin, float* __restrict__ xres) {
    int t = blockIdx.x * 256 + threadIdx.x;
    int h = t & (HID_ - 1);
    int bc = t >> 9;
    int b = bc >> 5, c = bc & (NCHUNK - 1);
    const float* p = proj + ((size_t)(b * S_ + c * CHUNK)) * (2 * HID_) + h;
    float* x = xres + ((size_t)(b * S_ + c * CHUNK)) * HID_ + h;
    float H = Hin[t];
#pragma unroll 4
    for (int s = 0; s < CHUNK; s++) {
        float k = p[(size_t)s * (2 * HID_)];
        float hp = p[(size_t)s * (2 * HID_) + HID_];
        float a, bb;
        gate_terms(k, hp, a, bb);
        H = a * H + bb;
        x[(size_t)s * HID_] += H;
    }
}

// ---------------- launch ----------------
extern "C" void kernel_launch(void* const* d_in, const int* in_sizes, int n_in,
                              void* d_out, int out_size, void* d_ws, size_t ws_size,
                              hipStream_t stream) {
    const int* ids = (const int*)d_in[0];
    const float* emb = (const float*)d_in[1];
    const float* W0 = (const float*)d_in[2];
    const float* W1 = (const float*)d_in[3];
    const float* ln0_g = (const float*)d_in[4];
    const float* ln0_b = (const float*)d_in[5];
    const float* ln1_g = (const float*)d_in[6];
    const float* ln1_b = (const float*)d_in[7];
    const float* lnf_g = (const float*)d_in[8];
    const float* lnf_b = (const float*)d_in[9];
    const float* fc_w = (const float*)d_in[10];
    const float* fc_b = (const float*)d_in[11];
    float* out = (float*)d_out;

    (void)hipFuncSetAttribute((const void*)gemm256_bf16_k,
                              hipFuncAttributeMaxDynamicSharedMemorySize, 131072);

    char* ws = (char*)d_ws;
    const size_t OFF_XW   = 0;                          // bf16 [8192][512]   8.4 MB
    const size_t OFF_PROJ = 8388608;                    // f32  [8192][1024] 33.6 MB
    const size_t OFF_XRES = OFF_PROJ + 33554432;        // f32  [8192][512]  16.8 MB
    const size_t OFF_WT   = OFF_XRES + 16777216;        // bf16 [1024][512]   1.05 MB
    const size_t OFF_SA   = OFF_WT + 1048576;
    const size_t OFF_SB   = OFF_SA + 262144;
    const size_t OFF_SH   = OFF_SB + 262144;

    unsigned short* xw  = (unsigned short*)(ws + OFF_XW);
    float* proj         = (float*)(ws + OFF_PROJ);
    float* xres         = (float*)(ws + OFF_XRES);
    unsigned short* wt  = (unsigned short*)(ws + OFF_WT);
    unsigned short* fcwt = (unsigned short*)(ws + OFF_PROJ);  // reuse proj after scans
    float* sA = (float*)(ws + OFF_SA);
    float* sB = (float*)(ws + OFF_SB);
    float* sH = (float*)(ws + OFF_SH);

    dim3 tb(32, 8);

    // layer 0
    embed_ln_k<<<ROWS / 4, 256, 0, stream>>>(ids, emb, ln0_g, ln0_b, xres, xw);
    transpose_convert_k<<<dim3(1024 / 32, 512 / 32), tb, 0, stream>>>(W0, wt, 512, 1024);
    gemm_bf16_k<<<dim3(1024 / 128, ROWS / 128), 256, 0, stream>>>(xw, wt, nullptr, proj, ROWS, 1024, 512);
    scan1_k<<<65536 / 256, 256, 0, stream>>>(proj, sA, sB);
    scan2_k<<<2048 / 256, 256, 0, stream>>>(sA, sB, sH);
    scan3_k<<<65536 / 256, 256, 0, stream>>>(proj, sH, xres);

    // layer 1
    ln_k<<<ROWS / 4, 256, 0, stream>>>(xres, ln1_g, ln1_b, xw, 1e-5f);
    transpose_convert_k<<<dim3(1024 / 32, 512 / 32), tb, 0, stream>>>(W1, wt, 512, 1024);
    gemm_bf16_k<<<dim3(1024 / 128, ROWS / 128), 256, 0, stream>>>(xw, wt, nullptr, proj, ROWS, 1024, 512);
    scan1_k<<<65536 / 256, 256, 0, stream>>>(proj, sA, sB);
    scan2_k<<<2048 / 256, 256, 0, stream>>>(sA, sB, sH);
    scan3_k<<<65536 / 256, 256, 0, stream>>>(proj, sH, xres);

    // final LN (eps=0.0) + logits via 256^2 8-phase GEMM
    ln_k<<<ROWS / 4, 256, 0, stream>>>(xres, lnf_g, lnf_b, xw, 0.0f);
    transpose_convert_k<<<dim3(VOCAB_ / 32, 512 / 32), tb, 0, stream>>>(fc_w, fcwt, 512, VOCAB_);
    {
        int nbm = ROWS / 256, nbn = VOCAB_ / 256;   // 32 x 125 = 4000 blocks
        gemm256_bf16_k<<<nbm * nbn, 512, 131072, stream>>>(xw, fcwt, fc_b, out, ROWS, VOCAB_, 512, nbn);
    }
}